// Round 4
// baseline (222.313 us; speedup 1.0000x reference)
//
#include <hip/hip_runtime.h>
#include <hip/hip_bf16.h>

// Problem constants: B=64, S=512, H=768, L=9
#define NB 64
#define NS 512
#define NH 768
#define NL 9
#define NROWS (NB*NS)          // 32768
#define EMN (NROWS*NL)         // 294912

// per-batch LDS strides (padded off %32==0 to avoid 4-way batch bank aliasing)
#define VST  4617              // floats per batch for s_v   (>= 512*9=4608; 4617-4608=9 pad slots)
#define BPST 4616              // bytes  per batch for s_bp  (>= 4608)

__device__ __forceinline__ float readlane_f(float v, int l) {
    return __int_as_float(__builtin_amdgcn_readlane(__float_as_int(v), l));
}
__device__ __forceinline__ unsigned long long readlane_u64(unsigned long long v, int l) {
    unsigned int lo = (unsigned int)__builtin_amdgcn_readlane((int)(unsigned int)(v & 0xffffffffULL), l);
    unsigned int hi = (unsigned int)__builtin_amdgcn_readlane((int)(unsigned int)(v >> 32), l);
    return ((unsigned long long)hi << 32) | (unsigned long long)lo;
}
// DPP add: x += dpp_move(x, CTRL); out-of-bound source lanes contribute 0.
template <int CTRL>
__device__ __forceinline__ float dpp_add(float x) {
    int t = __builtin_amdgcn_update_dpp(0, __float_as_int(x), CTRL, 0xf, 0xf, false);
    return x + __int_as_float(t);
}
// Canonical gfx9 wave64 sum; total lands in lane 63. Pure VALU (no LDS pipe).
__device__ __forceinline__ float wave_sum_to63(float x) {
    x = dpp_add<0x111>(x);  // row_shr:1
    x = dpp_add<0x112>(x);  // row_shr:2
    x = dpp_add<0x114>(x);  // row_shr:4
    x = dpp_add<0x118>(x);  // row_shr:8  (lane15 of each row = row sum)
    x = dpp_add<0x142>(x);  // row_bcast:15
    x = dpp_add<0x143>(x);  // row_bcast:31 -> lane63 = wave sum
    return x;
}
// ds_swizzle row-broadcast: every lane receives the value held by lane I of its
// own 16-lane row. BitMode offset = (xor<<10) | (or<<5) | and -> (I<<5) | 0x10.
template <int I>
__device__ __forceinline__ float rowbc(float x) {
    return __int_as_float(__builtin_amdgcn_ds_swizzle(__float_as_int(x), (I << 5) | 0x10));
}
// DPP row rotate (within each 16-lane row) — pure VALU cross-lane, no LDS pipe.
// row_ror:R ctrl = 0x120 + R. Source-lane convention is runtime-probed below.
template <int R>
__device__ __forceinline__ float ror_f(float x) {
    return __int_as_float(__builtin_amdgcn_update_dpp(0, __float_as_int(x), 0x120 + R, 0xf, 0xf, false));
}
__device__ __forceinline__ int ror1_i(int x) {
    return __builtin_amdgcn_update_dpp(0, x, 0x121, 0xf, 0xf, false);
}

// ---------------- Kernel A: emissions GEMM (K split across waves) ----------------
// (R0/R2-proven version; three structurally different variants all timed the same,
//  i.e. this kernel is already at its memory/latency floor — leave it alone.)
__global__ __launch_bounds__(256) void k_gemm(const float* __restrict__ hidden,
                                              const float* __restrict__ W,
                                              const float* __restrict__ bias,
                                              float* __restrict__ em,
                                              float* __restrict__ out) {
    __shared__ float s_part[4][4][NL];   // [wave][row][j]
    int tid = threadIdx.x;
    int lane = tid & 63;
    int w = tid >> 6;
    int bx = blockIdx.x;
    if (bx == 0 && tid == 0) { out[0] = 0.f; out[1] = 0.f; }

    int kbase = 192 * w + lane;          // + 64c, c=0..2
    float Wv[3][NL];
#pragma unroll
    for (int c = 0; c < 3; c++) {
        const float* wp = W + (size_t)(kbase + 64 * c) * NL;
#pragma unroll
        for (int j = 0; j < NL; j++) Wv[c][j] = wp[j];
    }

#pragma unroll
    for (int r = 0; r < 4; r++) {
        int row = 4 * bx + r;
        const float* hp = hidden + (size_t)row * NH + kbase;
        float h0 = hp[0], h1 = hp[64], h2 = hp[128];
        float acc[NL];
#pragma unroll
        for (int j = 0; j < NL; j++) {
            acc[j] = fmaf(h0, Wv[0][j], fmaf(h1, Wv[1][j], h2 * Wv[2][j]));
        }
#pragma unroll
        for (int j = 0; j < NL; j++) acc[j] = wave_sum_to63(acc[j]);
        if (lane == 63) {
#pragma unroll
            for (int j = 0; j < NL; j++) s_part[w][r][j] = acc[j];
        }
    }
    __syncthreads();
    if (tid < 36) {
        int r = tid / NL, j = tid % NL;
        float v = (s_part[0][r][j] + s_part[1][r][j]) +
                  (s_part[2][r][j] + s_part[3][r][j]) + bias[j];
        em[(size_t)(4 * bx + r) * NL + j] = v;
    }
}

// ---------------- Kernel B: DP + finalize ----------------
// 4 batches per chain-wave (one per 16-lane row). The 9-state broadcast per step
// is done with 15 DPP row_ror rotations (pure VALU, ~2cy issue each) against
// per-lane precomputed rotated operand tables, replacing 9 ds_swizzle round
// trips (~160cy of LDS-pipe serialization) on the serial critical path.
// Pad lanes (jcol 9..15) are neutralized via the tables: -inf for max-plus
// (never wins an exact max), 0-weight for the linear-domain forward.
__global__ __launch_bounds__(256) void k_dp(const float* __restrict__ em,
                                            const int* __restrict__ label,
                                            const int* __restrict__ mask,
                                            const float* __restrict__ startT,
                                            const float* __restrict__ endT,
                                            const float* __restrict__ trans,
                                            float* __restrict__ out) {
    __shared__ float s_T[NL * NL];
    __shared__ int s_mki[4][NS];                 // masks for the block's 4 batches
    __shared__ float s_v[4 * VST];               // viterbi value history (padded stride)
    __shared__ unsigned char s_bp[4 * BPST];     // backpointers
    __shared__ unsigned char s_path[4 * NS];     // decoded paths

    int bx = blockIdx.x;
    int tid = threadIdx.x;
    int lane = tid & 63;
    bool isfwd = bx < 16;
    int b0 = (isfwd ? bx : (bx - 16)) * 4;

    if (tid < NL * NL) s_T[tid] = trans[tid];
    if (isfwd) {
        for (int q = tid; q < 4 * NS / 4; q += 256)
            ((int4*)s_mki)[q] = ((const int4*)(mask + b0 * NS))[q];
    }
    __syncthreads();

    if (isfwd) {
        if (tid < 64) {
            // ---- forward algorithm, 4 batches (one per 16-lane row) ----
            int jcol = lane & 15;
            int jcol9 = jcol < NL ? jcol : NL - 1;
            const float* gp = em + (size_t)(b0 + (lane >> 4)) * (NS * NL) + jcol9;
            // probe row_ror:1 source-lane convention (robust to direction)
            int s1 = ror1_i(jcol);
            int step = (s1 - jcol) & 15;         // lane-uniform: 1 or 15
            // rotated operand tables: slot r pairs with a-value arriving at rotation r
            float Prot[16], Vrot[16];
            {
                int idx = jcol;
#pragma unroll
                for (int r = 0; r < 16; r++) {
                    bool valid = (jcol < NL) && (idx < NL);
                    Prot[r] = valid ? __expf(s_T[idx * NL + jcol]) : 0.f;
                    Vrot[r] = valid ? 1.f : 0.f;
                    idx = (idx + step) & 15;
                }
            }
            float a = __expf(startT[jcol9] + gp[0]);
            int eacc = 0;

#define ROT16(SRC_, R1_,R2_,R3_,R4_,R5_,R6_,R7_,R8_,R9_,R10_,R11_,R12_,R13_,R14_,R15_) \
    float R1_ = ror_f<1>(SRC_),  R2_ = ror_f<2>(SRC_),  R3_ = ror_f<3>(SRC_); \
    float R4_ = ror_f<4>(SRC_),  R5_ = ror_f<5>(SRC_),  R6_ = ror_f<6>(SRC_); \
    float R7_ = ror_f<7>(SRC_),  R8_ = ror_f<8>(SRC_),  R9_ = ror_f<9>(SRC_); \
    float R10_ = ror_f<10>(SRC_), R11_ = ror_f<11>(SRC_), R12_ = ror_f<12>(SRC_); \
    float R13_ = ror_f<13>(SRC_), R14_ = ror_f<14>(SRC_), R15_ = ror_f<15>(SRC_)

#define FBODY(EC_, KC_) do { \
    ROT16(a, q1,q2,q3,q4,q5,q6,q7,q8,q9,q10,q11,q12,q13,q14,q15); \
    float _s = ((( a*Prot[0]  + q1*Prot[1])  + (q2*Prot[2]   + q3*Prot[3])) \
             +  ((q4*Prot[4]  + q5*Prot[5])  + (q6*Prot[6]   + q7*Prot[7]))) \
             + (((q8*Prot[8]  + q9*Prot[9])  + (q10*Prot[10] + q11*Prot[11])) \
             +  ((q12*Prot[12]+ q13*Prot[13])+ (q14*Prot[14] + q15*Prot[15]))); \
    float _an = (EC_) * _s; \
    a = ((KC_) > 0) ? _an : a; \
} while (0)

#define FREN() do { \
    ROT16(a, c1,c2,c3,c4,c5,c6,c7,c8,c9,c10,c11,c12,c13,c14,c15); \
    float _c = ((( a*Vrot[0]  + c1*Vrot[1])  + (c2*Vrot[2]   + c3*Vrot[3])) \
             +  ((c4*Vrot[4]  + c5*Vrot[5])  + (c6*Vrot[6]   + c7*Vrot[7]))) \
             + (((c8*Vrot[8]  + c9*Vrot[9])  + (c10*Vrot[10] + c11*Vrot[11])) \
             +  ((c12*Vrot[12]+ c13*Vrot[13])+ (c14*Vrot[14] + c15*Vrot[15]))); \
    float _cu = rowbc<0>(_c);                /* row-uniform scale (pow2-exact renorm) */ \
    int _ex = ((__float_as_int(_cu) >> 23) & 255) - 127; \
    a = ldexpf(a, -_ex); eacc += _ex; \
} while (0)

            float e8[8]; int k8[8];
            int bb = lane >> 4;
#pragma unroll
            for (int p = 0; p < 8; p++) {
                e8[p] = __expf(gp[(1 + p) * NL]);
                k8[p] = s_mki[bb][1 + p];
            }
            for (int t0 = 1; t0 <= NS - 15; t0 += 8) {   // t0 = 1,9,...,497
#pragma unroll
                for (int p = 0; p < 8; p++) {
                    int t = t0 + p;
                    float ec = e8[p]; int kc = k8[p];
                    int tn = t + 8; tn = tn > NS - 1 ? NS - 1 : tn;
                    e8[p] = __expf(gp[tn * NL]);         // prefetch 8 ahead
                    k8[p] = s_mki[bb][tn];
                    FBODY(ec, kc);
                    if (p == 7) FREN();                  // t = 8,16,...,504
                }
            }
#pragma unroll
            for (int p = 0; p < 7; p++) FBODY(e8[p], k8[p]);   // t = 505..511
#undef FBODY
#undef FREN
            float z = a * __expf(endT[jcol9]);
            ROT16(z, z1,z2,z3,z4,z5,z6,z7,z8,z9,z10,z11,z12,z13,z14,z15);
            float c = ((( z*Vrot[0]  + z1*Vrot[1])  + (z2*Vrot[2]   + z3*Vrot[3]))
                    +  ((z4*Vrot[4]  + z5*Vrot[5])  + (z6*Vrot[6]   + z7*Vrot[7])))
                    + (((z8*Vrot[8]  + z9*Vrot[9])  + (z10*Vrot[10] + z11*Vrot[11]))
                    +  ((z12*Vrot[12]+ z13*Vrot[13])+ (z14*Vrot[14] + z15*Vrot[15])));
            if (jcol == 0) {
                float lz = (float)eacc * 0.6931471805599453f + __logf(c);
                atomicAdd(out, lz * (1.0f / (float)NB));
            }
        } else if (tid < 128) {
            // ---- numerator (gold path score), one 16-lane group per batch ----
            int g = lane >> 4;
            int ll = lane & 15;
            int b = b0 + g;
            const int* lb = label + b * NS;
            const float* ge = em + (size_t)b * NS * NL;
            int h = 0, sl = 0;
            for (int cch = 0; cch < 4; cch++) {
                int la8[8]; int mk8[8];
#pragma unroll
                for (int r = 0; r < 8; r++) {
                    int t = ll * 32 + cch * 8 + r;
                    la8[r] = lb[t];
                    int m = s_mki[g][t];
                    if (t == 0) m = 1;
                    mk8[r] = m;
                }
#pragma unroll
                for (int r = 0; r < 8; r++) if (mk8[r] > 0) { h = 1; sl = la8[r]; }
            }
#pragma unroll
            for (int d = 1; d < 16; d <<= 1) {
                int ho = __shfl_up(h, d, 16);
                int so = __shfl_up(sl, d, 16);
                if (!h) { h = ho; sl = so; }
            }
            int lg = __shfl(sl, 15, 16);
            int incoming = __shfl_up(sl, 1, 16);
            int labz = lb[0];
            int prevr = (ll == 0) ? labz : incoming;
            float sc = 0.f;
            for (int cch = 0; cch < 4; cch++) {
                int la8[8]; int mk8[8]; float ev8[8];
#pragma unroll
                for (int r = 0; r < 8; r++) {
                    int t = ll * 32 + cch * 8 + r;
                    la8[r] = lb[t];
                    int m = s_mki[g][t];
                    if (t == 0) m = 1;
                    mk8[r] = m;
                }
#pragma unroll
                for (int r = 0; r < 8; r++) {
                    int t = ll * 32 + cch * 8 + r;
                    ev8[r] = ge[t * NL + la8[r]];
                }
#pragma unroll
                for (int r = 0; r < 8; r++) {
                    int t = ll * 32 + cch * 8 + r;
                    if (t > 0) {
                        float s = s_T[prevr * NL + la8[r]] + ev8[r];
                        sc += s * (float)mk8[r];
                    }
                    if (mk8[r] > 0) prevr = la8[r];
                }
            }
            if (ll == 0) sc += startT[labz] + ge[labz] + endT[lg];
#pragma unroll
            for (int d = 1; d < 16; d <<= 1) sc += __shfl_xor(sc, d, 16);
            if (ll == 0) atomicAdd(out, -sc * (1.0f / (float)NB));
        }
    } else {
        // ---- Viterbi phase 1: 4 value chains (one per 16-lane row), bit-exact ----
        // max over {9 exact fl(v_i+T_ij) terms, 7 -inf pads} == ref's 9-term max.
        if (tid < 64) {
            int bb = lane >> 4;
            int jcol = lane & 15;
            int jcol9 = jcol < NL ? jcol : NL - 1;
            const float* gv = em + (size_t)(b0 + bb) * (NS * NL) + jcol9;
            int s1 = ror1_i(jcol);
            int step = (s1 - jcol) & 15;
            float Trot[16];
            {
                int idx = jcol;
#pragma unroll
                for (int r = 0; r < 16; r++) {
                    bool valid = (jcol < NL) && (idx < NL);
                    Trot[r] = valid ? s_T[idx * NL + jcol] : -__builtin_inff();
                    idx = (idx + step) & 15;
                }
            }
            float v = startT[jcol9] + gv[0];
            int svbase = bb * VST + jcol;
            // lanes 9..15 write slots overwritten by the next step's valid lanes
            s_v[svbase] = v;   // t = 0

#define VBODY(EC_, T_) do { \
    ROT16(v, r1,r2,r3,r4,r5,r6,r7,r8,r9,r10,r11,r12,r13,r14,r15); \
    float _m0 = v   + Trot[0],  _m1 = r1  + Trot[1],  _m2 = r2  + Trot[2]; \
    float _m3 = r3  + Trot[3],  _m4 = r4  + Trot[4],  _m5 = r5  + Trot[5]; \
    float _m6 = r6  + Trot[6],  _m7 = r7  + Trot[7],  _m8 = r8  + Trot[8]; \
    float _m9 = r9  + Trot[9],  _m10 = r10 + Trot[10], _m11 = r11 + Trot[11]; \
    float _m12 = r12 + Trot[12], _m13 = r13 + Trot[13], _m14 = r14 + Trot[14]; \
    float _m15 = r15 + Trot[15]; \
    float _A1 = fmaxf(fmaxf(_m0, _m1), _m2); \
    float _A2 = fmaxf(fmaxf(_m3, _m4), _m5); \
    float _A3 = fmaxf(fmaxf(_m6, _m7), _m8); \
    float _A4 = fmaxf(fmaxf(_m9, _m10), _m11); \
    float _A5 = fmaxf(fmaxf(_m12, _m13), _m14); \
    float _B1 = fmaxf(fmaxf(_A1, _A2), _A3); \
    float _B2 = fmaxf(fmaxf(_A4, _A5), _m15); \
    v = fmaxf(_B1, _B2) + (EC_); \
    s_v[svbase + (T_) * NL] = v; \
} while (0)

            float e8[8];
#pragma unroll
            for (int p = 0; p < 8; p++) e8[p] = gv[(1 + p) * NL];
            for (int t0 = 1; t0 <= NS - 15; t0 += 8) {
#pragma unroll
                for (int p = 0; p < 8; p++) {
                    int t = t0 + p;
                    float ec = e8[p];
                    int tn = t + 8; tn = tn > NS - 1 ? NS - 1 : tn;
                    e8[p] = gv[tn * NL];
                    VBODY(ec, t);
                }
            }
#pragma unroll
            for (int p = 0; p < 7; p++) VBODY(e8[p], 505 + p);
#undef VBODY
        }
        __syncthreads();
        // ---- phase 2: backpointers, parallel over (batch, t); exact ref op order ----
        for (int it = 0; it < 8; it++) {
            int item = tid + it * 256;
            int bb = item >> 9;
            int t = item & (NS - 1);
            if (t > 0) {
                const float* vpp = s_v + bb * VST + (t - 1) * NL;
                const float* ge = em + (size_t)(b0 + bb) * (NS * NL) + t * NL;
                float vp[NL], emt[NL];
#pragma unroll
                for (int i = 0; i < NL; i++) vp[i] = vpp[i];
#pragma unroll
                for (int j = 0; j < NL; j++) emt[j] = ge[j];
#pragma unroll
                for (int j = 0; j < NL; j++) {
                    float e = emt[j];
                    float val[NL];
#pragma unroll
                    for (int i = 0; i < NL; i++) val[i] = (vp[i] + s_T[i * NL + j]) + e;
                    bool c01 = val[0] >= val[1]; float m01 = c01 ? val[0] : val[1]; int i01 = c01 ? 0 : 1;
                    bool c23 = val[2] >= val[3]; float m23 = c23 ? val[2] : val[3]; int i23 = c23 ? 2 : 3;
                    bool c45 = val[4] >= val[5]; float m45 = c45 ? val[4] : val[5]; int i45 = c45 ? 4 : 5;
                    bool c67 = val[6] >= val[7]; float m67 = c67 ? val[6] : val[7]; int i67 = c67 ? 6 : 7;
                    bool ca = m01 >= m23; float ma = ca ? m01 : m23; int ia = ca ? i01 : i23;
                    bool cb = m45 >= m67; float mb = cb ? m45 : m67; int ib = cb ? i45 : i67;
                    bool cc = ma >= mb;  float mc = cc ? ma : mb;  int ic = cc ? ia : ib;
                    bool cd = mc >= val[8]; int bi = cd ? ic : 8;
                    s_bp[bb * BPST + t * NL + j] = (unsigned char)bi;
                }
            }
        }
        __syncthreads();
        // ---- phase 3: last tag + map-composition backtrack (wave w -> batch w) ----
        {
            int w = tid >> 6;
            const float* sv = s_v + w * VST;
            const unsigned char* bpp = s_bp + w * BPST;
            unsigned char* pth = s_path + w * NS;
            float bb2 = sv[(NS - 1) * NL + 0] + endT[0]; int lt = 0;
#pragma unroll
            for (int jj = 1; jj < NL; jj++) {
                float fj = sv[(NS - 1) * NL + jj] + endT[jj];
                if (fj > bb2) { bb2 = fj; lt = jj; }
            }
            unsigned long long G[8];
#pragma unroll
            for (int r = 0; r < 8; r++) {
                int t0 = (lane * 8 + r) * NL;
                unsigned long long g = 0;
                if (lane == 0 && r == 0) {
                    g = 0x876543210ULL;   // t=0 identity (bp[0] unused)
                } else {
#pragma unroll
                    for (int x = 0; x < NL; x++) g |= (unsigned long long)bpp[t0 + x] << (4 * x);
                }
                G[r] = g;
            }
            unsigned long long A = 0x876543210ULL;
#pragma unroll
            for (int r = 7; r >= 0; r--) {
                unsigned long long An = 0;
#pragma unroll
                for (int x = 0; x < NL; x++) {
                    int ax = (int)((A >> (4 * x)) & 15ULL);
                    int gvv = (int)((G[r] >> (4 * ax)) & 15ULL);
                    An |= (unsigned long long)gvv << (4 * x);
                }
                A = An;
            }
            int e = 0; int cur = lt;
            for (int llv = 63; llv >= 0; --llv) {
                if (lane == llv) e = cur;
                unsigned long long Al = readlane_u64(A, llv);
                cur = (int)((Al >> (4 * cur)) & 15ULL);
            }
            unsigned long long pw = 0; int c2 = e;
#pragma unroll
            for (int r = 7; r >= 0; r--) {
                pw |= (unsigned long long)c2 << (8 * r);
                c2 = (int)((G[r] >> (4 * c2)) & 15ULL);
            }
            *(unsigned long long*)(pth + lane * 8) = pw;
        }
        __syncthreads();
        // ---- finalize: predict/label/correct for the block's 4 batches ----
        float cnt = 0.f;
#pragma unroll
        for (int q = 0; q < 8; q++) {
            int item = tid + q * 256;
            int bb = item >> 9;
            int t = item & (NS - 1);
            int b = b0 + bb;
            int idx = b * NS + t;
            int lab = label[idx];
            int p = (int)s_path[bb * NS + t];
            int pred = (lab > 0) ? p : 0;
            out[2 + idx] = (float)pred;
            out[2 + NROWS + idx] = (float)lab;
            cnt += (pred == lab) ? 1.f : 0.f;
        }
#pragma unroll
        for (int d = 1; d < 64; d <<= 1) cnt += __shfl_xor(cnt, d);
        if ((tid & 63) == 0) atomicAdd(out + 1, cnt);
    }
}

extern "C" void kernel_launch(void* const* d_in, const int* in_sizes, int n_in,
                              void* d_out, int out_size, void* d_ws, size_t ws_size,
                              hipStream_t stream) {
    const float* hidden = (const float*)d_in[0];
    const int*   label  = (const int*)d_in[1];
    const int*   mask   = (const int*)d_in[2];
    const float* W      = (const float*)d_in[3];
    const float* bias   = (const float*)d_in[4];
    const float* startT = (const float*)d_in[5];
    const float* endT   = (const float*)d_in[6];
    const float* trans  = (const float*)d_in[7];
    float* out = (float*)d_out;

    float* em = (float*)d_ws;   // EMN floats

    k_gemm<<<8192, 256, 0, stream>>>(hidden, W, bias, em, out);
    k_dp<<<32, 256, 0, stream>>>(em, label, mask, startT, endT, trans, out);
}